// Round 6
// baseline (410.262 us; speedup 1.0000x reference)
//
#include <hip/hip_runtime.h>
#include <math.h>

#define NN 4096

typedef __bf16 bf16;
typedef __attribute__((ext_vector_type(8))) __bf16 bf16x8;
typedef __attribute__((ext_vector_type(4))) float f32x4;

__device__ __forceinline__ void gld16(const void* g, void* l) {
  __builtin_amdgcn_global_load_lds((const __attribute__((address_space(1))) void*)g,
                                   (__attribute__((address_space(3))) void*)l, 16, 0, 0);
}

// ---------- block reduction helpers (blockDim.x == 256) ----------

__device__ __forceinline__ double blockSumD(double v) {
  __shared__ double w[4];
  #pragma unroll
  for (int o = 32; o > 0; o >>= 1) v += __shfl_down(v, o, 64);
  __syncthreads();
  if ((threadIdx.x & 63) == 0) w[threadIdx.x >> 6] = v;
  __syncthreads();
  return w[0] + w[1] + w[2] + w[3];
}

__device__ __forceinline__ float blockMaxF(float v) {
  __shared__ float w[4];
  #pragma unroll
  for (int o = 32; o > 0; o >>= 1) v = fmaxf(v, __shfl_down(v, o, 64));
  __syncthreads();
  if ((threadIdx.x & 63) == 0) w[threadIdx.x >> 6] = v;
  __syncthreads();
  return fmaxf(fmaxf(w[0], w[1]), fmaxf(w[2], w[3]));
}

// ---------- kernel 1: row softmax of x,y -> bf16 (16B stores), row sum-of-squares ----------
// Thread t owns contiguous elements [16t, 16t+16) of its row -> two bf16x8 stores.

__global__ void softmax_rows(const float* __restrict__ x, const float* __restrict__ y,
                             bf16* __restrict__ xh, bf16* __restrict__ yh,
                             float* __restrict__ rowsq, float* __restrict__ out) {
  int row = blockIdx.x;
  int t = threadIdx.x;
  if (row == 0 && t == 0) out[0] = 0.0f;  // init for cost atomics in pi_cost
  int r = (row < NN) ? row : row - NN;
  const f32x4* __restrict__ src = (const f32x4*)(((row < NN) ? x : y) + (size_t)r * NN);
  bf16x8* __restrict__ dst = (bf16x8*)(((row < NN) ? xh : yh) + (size_t)r * NN);

  f32x4 v[4];
  float m = -3.402823466e38f;
  #pragma unroll
  for (int j = 0; j < 4; ++j) {
    v[j] = src[4 * t + j];
    m = fmaxf(fmaxf(fmaxf(m, v[j].x), fmaxf(v[j].y, v[j].z)), v[j].w);
  }
  float M = blockMaxF(m);

  float s = 0.0f;
  #pragma unroll
  for (int j = 0; j < 4; ++j) {
    v[j].x = __expf(v[j].x - M); v[j].y = __expf(v[j].y - M);
    v[j].z = __expf(v[j].z - M); v[j].w = __expf(v[j].w - M);
    s += (v[j].x + v[j].y) + (v[j].z + v[j].w);
  }
  double S = blockSumD((double)s);
  float inv = (float)(1.0 / S);

  float q = 0.0f;
  #pragma unroll
  for (int j = 0; j < 2; ++j) {
    f32x4 p0 = v[2 * j] * inv;
    f32x4 p1 = v[2 * j + 1] * inv;
    bf16x8 h;
    h[0] = (bf16)p0.x; h[1] = (bf16)p0.y; h[2] = (bf16)p0.z; h[3] = (bf16)p0.w;
    h[4] = (bf16)p1.x; h[5] = (bf16)p1.y; h[6] = (bf16)p1.z; h[7] = (bf16)p1.w;
    dst[2 * t + j] = h;
    q += (p0.x * p0.x + p0.y * p0.y) + (p0.z * p0.z + p0.w * p0.w);
    q += (p1.x * p1.x + p1.y * p1.y) + (p1.z * p1.z + p1.w * p1.w);
  }
  double Q = blockSumD((double)q);
  if (t == 0) rowsq[row] = (float)Q;
}

// ---------- kernel 2: C = x2 + y2 - 2 * sx . sy^T  (bf16 MFMA) + fused column exp-sums ----------
// 128x128 tile, BK=64, 4 waves, 4x4 16x16x32 MFMA tiles/wave. XOR-swizzled LDS (0 conflicts).
// NOTE: 88 VGPR + 64 AGPR = 152 unified regs -> 3 blocks/CU (round-4 lesson: never assume 4).

__global__ __launch_bounds__(256) void gemm_bt(const bf16* __restrict__ A,
                                               const bf16* __restrict__ B,
                                               const float* __restrict__ rowsq,
                                               float* __restrict__ C,
                                               float* __restrict__ colpart) {
  __shared__ __align__(16) bf16 As[128 * 64];
  __shared__ __align__(16) bf16 Bs[128 * 64];
  __shared__ float lsc[2][128];
  int t = threadIdx.x;
  int i0 = blockIdx.y * 128;
  int j0 = blockIdx.x * 128;
  int w = t >> 6, l = t & 63;
  int mrow = (w >> 1) * 64, ncol = (w & 1) * 64;
  int lr = l & 15, lq = l >> 4;

  f32x4 acc[4][4] = {};

  for (int kc = 0; kc < NN; kc += 64) {
    __syncthreads();
    #pragma unroll
    for (int q = 0; q < 4; ++q) {
      int c = t + 256 * q;              // LDS chunk index 0..1023
      int row = c >> 3;
      int jg = (c & 7) ^ (row & 7);     // swizzled source chunk within the row
      gld16(A + (size_t)(i0 + row) * NN + kc + jg * 8, (char*)As + c * 16);
    }
    #pragma unroll
    for (int q = 0; q < 4; ++q) {
      int c = t + 256 * q;
      int row = c >> 3;
      int jg = (c & 7) ^ (row & 7);
      gld16(B + (size_t)(j0 + row) * NN + kc + jg * 8, (char*)Bs + c * 16);
    }
    __syncthreads();

    #pragma unroll
    for (int s = 0; s < 2; ++s) {
      bf16x8 af[4], bg[4];
      #pragma unroll
      for (int i = 0; i < 4; ++i) {
        int ra = mrow + 16 * i + lr;
        int ja = (s * 4 + lq) ^ (ra & 7);
        af[i] = *(const bf16x8*)((const char*)As + (ra * 8 + ja) * 16);
        int rb = ncol + 16 * i + lr;
        int jb = (s * 4 + lq) ^ (rb & 7);
        bg[i] = *(const bf16x8*)((const char*)Bs + (rb * 8 + jb) * 16);
      }
      #pragma unroll
      for (int i = 0; i < 4; ++i)
        #pragma unroll
        for (int jj = 0; jj < 4; ++jj)
          acc[i][jj] = __builtin_amdgcn_mfma_f32_16x16x32_bf16(af[i], bg[jj], acc[i][jj], 0, 0, 0);
    }
  }

  float y2v[4], ec[4] = {0.f, 0.f, 0.f, 0.f};
  #pragma unroll
  for (int jj = 0; jj < 4; ++jj) y2v[jj] = rowsq[NN + j0 + ncol + 16 * jj + lr];
  #pragma unroll
  for (int i = 0; i < 4; ++i) {
    #pragma unroll
    for (int r = 0; r < 4; ++r) {
      int grow = i0 + mrow + 16 * i + lq * 4 + r;
      float x2 = rowsq[grow];
      size_t rowoff = (size_t)grow * NN + j0 + ncol;
      #pragma unroll
      for (int jj = 0; jj < 4; ++jj) {
        float cv = x2 + y2v[jj] - 2.0f * acc[i][jj][r];
        C[rowoff + 16 * jj + lr] = cv;
        ec[jj] += __expf(-10.0f * cv);
      }
    }
  }
  // reduce over lq (lanes lr, lr+16, lr+32, lr+48 hold the same columns)
  #pragma unroll
  for (int jj = 0; jj < 4; ++jj) {
    ec[jj] += __shfl_xor(ec[jj], 16, 64);
    ec[jj] += __shfl_xor(ec[jj], 32, 64);
  }
  if (lq == 0) {
    #pragma unroll
    for (int jj = 0; jj < 4; ++jj) lsc[w >> 1][ncol + 16 * jj + lr] = ec[jj];
  }
  __syncthreads();
  if (t < 128) colpart[(size_t)blockIdx.y * NN + j0 + t] = lsc[0][t] + lsc[1][t];
}

// ---------- kernel 3: sdfp[col] = log_nu - log(colsum), wrap-padded to 4100 ----------

__global__ void col_lse_final(const float* __restrict__ colpart, float* __restrict__ sdfp) {
  int col = blockIdx.x * 256 + threadIdx.x;
  double s = 0.0;
  #pragma unroll
  for (int ch = 0; ch < 32; ++ch) s += (double)colpart[(size_t)ch * NN + col];
  float val = (float)(-8.317725207557924 - log(s));  // log(1/4096+1e-8) - log(S_j)
  sdfp[col] = val;
  if (col < 4) sdfp[4096 + col] = val;  // wrap pad for quads straddling col 4095
}

// ---------- kernel 4: pi = exp(-10*C + s_j) + cost, 16B-aligned float4 body ----------
// pi and Cm share the +4B misalignment: elements e==3 (mod 4) start aligned float4s.
// Quad q covers elements 3+4q..6+4q; its col-quad = 3+4*(q mod 1024); a thread's 8
// quads use only 4 distinct col-quads (block*2048 == 0 mod 1024) -> preload 16 sdf.

__global__ void pi_cost(const float* __restrict__ Cm, const float* __restrict__ sdfp,
                        float* __restrict__ pi, float* __restrict__ out) {
  int t = threadIdx.x;
  float sj[4][4];
  #pragma unroll
  for (int jm = 0; jm < 4; ++jm) {
    int c0 = 3 + 4 * ((t + 256 * jm) & 1023);
    sj[jm][0] = sdfp[c0];     sj[jm][1] = sdfp[c0 + 1];
    sj[jm][2] = sdfp[c0 + 2]; sj[jm][3] = sdfp[c0 + 3];
  }
  size_t qbase = (size_t)blockIdx.x * 2048 + t;
  float facc = 0.0f;
  #pragma unroll
  for (int j = 0; j < 8; ++j) {
    size_t q = qbase + 256 * j;
    if (q < 4194303) {  // (NN*NN - 3) / 4 full quads
      const f32x4 c = *(const f32x4*)(Cm + 3 + 4 * q);
      f32x4 p;
      p.x = __expf(fmaf(-10.0f, c.x, sj[j & 3][0]));
      p.y = __expf(fmaf(-10.0f, c.y, sj[j & 3][1]));
      p.z = __expf(fmaf(-10.0f, c.z, sj[j & 3][2]));
      p.w = __expf(fmaf(-10.0f, c.w, sj[j & 3][3]));
      *(f32x4*)(pi + 3 + 4 * q) = p;
      facc = fmaf(p.x, c.x, facc); facc = fmaf(p.y, c.y, facc);
      facc = fmaf(p.z, c.z, facc); facc = fmaf(p.w, c.w, facc);
    }
  }
  if (blockIdx.x == 0 && t == 0) {  // stragglers: e = 0,1,2 and NN*NN-1
    const size_t es[4] = {0, 1, 2, (size_t)NN * NN - 1};
    #pragma unroll
    for (int k = 0; k < 4; ++k) {
      size_t e = es[k];
      float cv = Cm[e];
      float p = __expf(fmaf(-10.0f, cv, sdfp[(int)(e & (NN - 1))]));
      pi[e] = p;
      facc = fmaf(p, cv, facc);
    }
  }
  double total = blockSumD((double)facc);
  if (t == 0) atomicAdd(out, (float)total);
}

// ---------- launch ----------

extern "C" void kernel_launch(void* const* d_in, const int* in_sizes, int n_in,
                              void* d_out, int out_size, void* d_ws, size_t ws_size,
                              hipStream_t stream) {
  const float* x = (const float*)d_in[0];
  const float* y = (const float*)d_in[1];
  float* out = (float*)d_out;
  float* pi = out + 1;                          // [NN*NN] floats (+4B phase)
  float* Cm = out + 1 + (size_t)NN * NN;        // [NN*NN] floats (+4B phase)

  char* ws = (char*)d_ws;
  bf16* xh = (bf16*)ws;                                          // 32 MiB
  bf16* yh = xh + (size_t)NN * NN;                               // 32 MiB
  size_t off = (size_t)NN * NN * 2 * 2;
  float* rowsq = (float*)(ws + off);       off += 2 * NN * 4;    // 32 KiB
  float* colpart = (float*)(ws + off);     off += 32 * NN * 4;   // 512 KiB
  float* sdfp = (float*)(ws + off);        off += 4100 * 4;      // 16.4 KiB

  hipLaunchKernelGGL(softmax_rows, dim3(2 * NN), dim3(256), 0, stream, x, y, xh, yh, rowsq, out);
  hipLaunchKernelGGL(gemm_bt, dim3(32, 32), dim3(256), 0, stream, xh, yh, rowsq, Cm, colpart);
  hipLaunchKernelGGL(col_lse_final, dim3(16), dim3(256), 0, stream, colpart, sdfp);
  hipLaunchKernelGGL(pi_cost, dim3(2048), dim3(256), 0, stream, Cm, sdfp, pi, out);
}